// Round 19
// baseline (548.932 us; speedup 1.0000x reference)
//
#include <hip/hip_runtime.h>
#include <cstdint>

typedef unsigned short u16;
typedef __attribute__((ext_vector_type(8))) __bf16 bf16x8;
typedef __attribute__((ext_vector_type(4))) float f32x4;

#define NTOK 8192
#define DM   1024
#define DFF  4096
#define NE   8
#define NT_MAX 136

typedef const __attribute__((address_space(1))) unsigned gl_u32;
typedef __attribute__((address_space(3))) unsigned lds_u32;

static __device__ __forceinline__ u16 f2bf(float f) {
    union { float f; unsigned u; } v; v.f = f;
    unsigned r = v.u + 0x7fffu + ((v.u >> 16) & 1u);
    return (u16)(r >> 16);
}

// -------- W [K][F] f32 -> WT [F][K] bf16, per expert in z; 64k x 32f tiles ------
__global__ __launch_bounds__(256) void transpose_cvt_kernel(const float* __restrict__ W,
                                                            u16* __restrict__ WT,
                                                            int K, int F) {
    __shared__ float tile[64][33];
    size_t eo = (size_t)blockIdx.z * K * F;
    const float* src = W + eo;
    u16* dst = WT + eo;
    int k0 = blockIdx.y * 64, f0 = blockIdx.x * 32;
    int tid = threadIdx.x;
    {
        int rk = tid >> 2, cf = (tid & 3) * 8;
        const float* s = src + (size_t)(k0 + rk) * F + f0 + cf;
        f32x4 v0 = *(const f32x4*)(s);
        f32x4 v1 = *(const f32x4*)(s + 4);
#pragma unroll
        for (int i = 0; i < 4; i++) { tile[rk][cf + i] = v0[i]; tile[rk][cf + 4 + i] = v1[i]; }
    }
    __syncthreads();
    {
        int f = tid >> 3, kq = (tid & 7) * 8;
        union { ushort4 h[2]; uint4 q; } o;
#pragma unroll
        for (int i = 0; i < 8; i++) {
            u16 b = f2bf(tile[kq + i][f]);
            ((u16*)&o)[i] = b;
        }
        *(uint4*)(dst + (size_t)(f0 + f) * K + k0 + kq) = o.q;
    }
}

// ------- gate: 512 thr / 8 waves x 4 tokens; block-aggregated routing ------------
__global__ __launch_bounds__(512) void gate_kernel(const float* __restrict__ x,
                                                   const float* __restrict__ gw,
                                                   u16* __restrict__ xb,
                                                   int* __restrict__ cnt,
                                                   float* __restrict__ psum,
                                                   float* __restrict__ indsum,
                                                   int* __restrict__ list,
                                                   float* __restrict__ wgt,
                                                   int4* __restrict__ tokIE,
                                                   float2* __restrict__ tokW) {
    __shared__ float s_psum[NE], s_ind[NE];
    __shared__ int s_cnt[NE], s_base[NE];
    __shared__ int s_tok[NE][32];
    __shared__ float s_wgt[NE][32];
    __shared__ int s_e1[32], s_p1[32], s_e2[32], s_p2[32];
    __shared__ float s_w1[32], s_w2[32];
    int tid = threadIdx.x, lane = tid & 63, wid = tid >> 6;
    if (tid < NE) { s_psum[tid] = 0.f; s_ind[tid] = 0.f; s_cnt[tid] = 0; }
    __syncthreads();
#pragma unroll 1
    for (int it = 0; it < 4; it++) {
        int sl = wid * 4 + it;
        int t = blockIdx.x * 32 + sl;
        const float* xr = x + (size_t)t * DM;
        float xv[16];
#pragma unroll
        for (int i = 0; i < 4; i++) {
            f32x4 v = *(const f32x4*)(xr + i * 256 + lane * 4);
            xv[4 * i + 0] = v[0]; xv[4 * i + 1] = v[1];
            xv[4 * i + 2] = v[2]; xv[4 * i + 3] = v[3];
            ushort4 o;
            o.x = f2bf(v[0]); o.y = f2bf(v[1]); o.z = f2bf(v[2]); o.w = f2bf(v[3]);
            *(ushort4*)(xb + (size_t)t * DM + i * 256 + lane * 4) = o;
        }
        float p[NE];
#pragma unroll
        for (int e = 0; e < NE; e++) {
            const float* gr = gw + (size_t)e * DM;
            float d = 0.f;
#pragma unroll
            for (int i = 0; i < 4; i++) {
                f32x4 g = *(const f32x4*)(gr + i * 256 + lane * 4);
                d += xv[4 * i] * g[0] + xv[4 * i + 1] * g[1]
                   + xv[4 * i + 2] * g[2] + xv[4 * i + 3] * g[3];
            }
#pragma unroll
            for (int off = 32; off; off >>= 1) d += __shfl_xor(d, off);
            p[e] = d;   // GATE_TEMP == 1
        }
        float m = p[0];
#pragma unroll
        for (int e = 1; e < NE; e++) m = fmaxf(m, p[e]);
        float s = 0.f;
#pragma unroll
        for (int e = 0; e < NE; e++) { p[e] = expf(p[e] - m); s += p[e]; }
        float inv = 1.f / s;
#pragma unroll
        for (int e = 0; e < NE; e++) p[e] *= inv;
        int i1 = 0; float p1 = p[0];
#pragma unroll
        for (int e = 1; e < NE; e++) if (p[e] > p1) { p1 = p[e]; i1 = e; }
        int i2 = (i1 == 0) ? 1 : 0; float p2 = p[i2];
#pragma unroll
        for (int e = 0; e < NE; e++) if (e != i1 && p[e] > p2) { p2 = p[e]; i2 = e; }
        float wnorm = 1.f / (p1 + p2);
        if (lane == 0) {
#pragma unroll
            for (int e = 0; e < NE; e++) {
                atomicAdd(&s_psum[e], p[e]);
                atomicAdd(&s_ind[e], (p[e] > 0.f) ? 1.f : 0.f);
            }
            int pos1 = atomicAdd(&s_cnt[i1], 1);
            s_tok[i1][pos1] = t; s_wgt[i1][pos1] = p1 * wnorm;
            int pos2 = atomicAdd(&s_cnt[i2], 1);
            s_tok[i2][pos2] = t; s_wgt[i2][pos2] = p2 * wnorm;
            s_e1[sl] = i1; s_p1[sl] = pos1; s_w1[sl] = p1 * wnorm;
            s_e2[sl] = i2; s_p2[sl] = pos2; s_w2[sl] = p2 * wnorm;
        }
    }
    __syncthreads();
    if (tid < NE) {
        s_base[tid] = atomicAdd(&cnt[tid], s_cnt[tid]);
        atomicAdd(&psum[tid], s_psum[tid]);
        atomicAdd(&indsum[tid], s_ind[tid]);
    }
    __syncthreads();
    for (int idx = tid; idx < NE * 32; idx += 512) {
        int e = idx >> 5, j = idx & 31;
        if (j < s_cnt[e]) {
            list[e * NTOK + s_base[e] + j] = s_tok[e][j];
            wgt[e * NTOK + s_base[e] + j] = s_wgt[e][j];
        }
    }
    if (tid < 32) {
        int t = blockIdx.x * 32 + tid;
        int e1 = s_e1[tid], e2 = s_e2[tid];
        tokIE[t] = make_int4(e1, s_base[e1] + s_p1[tid], e2, s_base[e2] + s_p2[tid]);
        tokW[t] = make_float2(s_w1[tid], s_w2[tid]);
    }
}

// ---------------- finalize: aux loss + expert bases + flat tile worklist ----------
__global__ void finalize_kernel(const float* __restrict__ psum,
                                const float* __restrict__ indsum,
                                const int* __restrict__ cnt,
                                int* __restrict__ baseArr,
                                int* __restrict__ tileE,
                                int* __restrict__ tileM0,
                                int* __restrict__ nTiles,
                                float* __restrict__ out_aux) {
    if (threadIdx.x == 0) {
        float a = 0.f; int b = 0, nt = 0;
        for (int e = 0; e < NE; e++) {
            a += (psum[e] * (1.f / NTOK)) * (indsum[e] * (1.f / NTOK));
            baseArr[e] = b; b += cnt[e];
            int mt = (cnt[e] + 127) >> 7;
            for (int i = 0; i < mt; i++) { tileE[nt] = e; tileM0[nt] = i; nt++; }
        }
        nTiles[0] = nt;
        out_aux[0] = a * (float)NE * 0.01f;
    }
}

// ---------------- m97-style single-buffer bf16 MFMA GEMM: 128x128, BK=64 ---------
// R13/R17 champion K-loop. launch_bounds(256) WITHOUT min-waves floor: kernel
// needs only 64 VGPR naturally; <=102 VGPR keeps 5-waves/SIMD eligibility and
// 32 KiB LDS admits 5 blocks/CU (vs 4 declared before). Cross-block overlap
// covers the per-tile staging drain (m114). T2 both-sides swizzle; T5 setprio;
// band worklist (4 m-tiles x all NY) + bijective XCD chunking.
// EPI==1: A = xb gathered via list; epilogue fast-gelu -> h[hb+p]
// EPI==2: A = h[hb+p]; epilogue pairOut[hb+p] = acc
// EPI==3: A = h[hb+p]; epilogue atomicAdd(out[tok], wgt*(acc+bias))  (fallback)
template <int KDIM, int EPI>
__global__ __launch_bounds__(256) void gemm_kernel(const u16* __restrict__ A,
                                                   const u16* __restrict__ BT,
                                                   const float* __restrict__ bias,
                                                   const int* __restrict__ list,
                                                   const float* __restrict__ wgt,
                                                   const int* __restrict__ cnt,
                                                   const int* __restrict__ base,
                                                   const int* __restrict__ tileE,
                                                   const int* __restrict__ tileM0,
                                                   const int* __restrict__ nTiles,
                                                   u16* __restrict__ h_out,
                                                   float* __restrict__ out) {
    constexpr int NCOL = (EPI == 1) ? DFF : DM;
    constexpr int NY = NCOL / 128;
    constexpr int NT = KDIM / 64;
    constexpr int BAND = 4 * NY;
    int nwg = gridDim.x;
    int q = nwg >> 3, r = nwg & 7;
    int xcd = blockIdx.x & 7, idx0 = blockIdx.x >> 3;
    int wg = (xcd < r ? xcd * (q + 1) : r * (q + 1) + (xcd - r) * q) + idx0;
    int band = wg / BAND, ib = wg - band * BAND;
    int ny = ib >> 2;
    int t = band * 4 + (ib & 3);
    if (t >= nTiles[0]) return;
    int e = tileE[t];
    int m0 = tileM0[t] << 7;
    int M = cnt[e];
    int hb = base[e];
    int n0 = ny * 128;
    const int* le = list + e * NTOK;
    const float* we = wgt + e * NTOK;
    const u16* Bte = BT + (size_t)e * NCOL * KDIM;
    const float* be = bias + (size_t)e * NCOL;

    // single-buffered: 16 KiB A + 16 KiB B = 32 KiB
    __shared__ __attribute__((aligned(16))) u16 lA[128 * 64];
    __shared__ __attribute__((aligned(16))) u16 lB[128 * 64];

    int tid = threadIdx.x;
    int lane = tid & 63, wid = tid >> 6;
    int wr = wid >> 1, wc = wid & 1;
    int r16 = lane & 15, hi = lane >> 4;
    int r8 = r16 & 7;

    const u16* aG[4]; const u16* bG[4]; int lofs[4];
#pragma unroll
    for (int qq = 0; qq < 4; qq++) {
        int lin = qq * 256 + tid;
        int row = lin >> 3, j = lin & 7;
        int js = j ^ (row & 7);                     // source-side swizzle
        lofs[qq] = lin * 8;
        int pos = m0 + row; if (pos > M - 1) pos = M - 1;
        size_t arow = (EPI == 1) ? (size_t)le[pos] : (size_t)(hb + pos);
        aG[qq] = A + arow * KDIM + js * 8;
        bG[qq] = Bte + (size_t)(n0 + row) * KDIM + js * 8;
    }

#define STAGE(k0)                                                                   \
    do {                                                                            \
        _Pragma("unroll")                                                           \
        for (int qq = 0; qq < 4; qq++) {                                            \
            __builtin_amdgcn_global_load_lds((gl_u32*)(aG[qq] + (k0)),              \
                (lds_u32*)(lA + lofs[qq]), 16, 0, 0);                               \
            __builtin_amdgcn_global_load_lds((gl_u32*)(bG[qq] + (k0)),              \
                (lds_u32*)(lB + lofs[qq]), 16, 0, 0);                               \
        }                                                                           \
    } while (0)

    f32x4 acc[4][4];
#pragma unroll
    for (int m = 0; m < 4; m++)
#pragma unroll
        for (int n = 0; n < 4; n++) acc[m][n] = (f32x4){0.f, 0.f, 0.f, 0.f};

    STAGE(0);

#pragma unroll 1
    for (int tI = 0; tI < NT; ++tI) {
        // tile tI staged by every wave -> visible after barrier
        asm volatile("s_waitcnt vmcnt(0)" ::: "memory");
        __builtin_amdgcn_s_barrier();
#pragma unroll
        for (int kk = 0; kk < 2; kk++) {
            bf16x8 aF[4], bF[4];
            int ch = ((kk << 2) | hi) ^ r8;         // read-side swizzle
#pragma unroll
            for (int m = 0; m < 4; m++)
                aF[m] = *(const bf16x8*)(lA + ((wr * 64 + m * 16 + r16) << 6) + (ch << 3));
#pragma unroll
            for (int n = 0; n < 4; n++)
                bF[n] = *(const bf16x8*)(lB + ((wc * 64 + n * 16 + r16) << 6) + (ch << 3));
            __builtin_amdgcn_s_setprio(1);
#pragma unroll
            for (int m = 0; m < 4; m++)
#pragma unroll
                for (int n = 0; n < 4; n++)
                    acc[m][n] = __builtin_amdgcn_mfma_f32_16x16x32_bf16(aF[m], bF[n], acc[m][n], 0, 0, 0);
            __builtin_amdgcn_s_setprio(0);
        }
        // all reads done -> safe to overwrite buffer with next tile
        asm volatile("s_waitcnt lgkmcnt(0)" ::: "memory");
        __builtin_amdgcn_s_barrier();
        if (tI + 1 < NT) STAGE((tI + 1) * 64);
    }
#undef STAGE

#pragma unroll
    for (int m = 0; m < 4; m++) {
        int pr = m0 + wr * 64 + m * 16 + hi * 4;
#pragma unroll
        for (int n = 0; n < 4; n++) {
            int f = n0 + wc * 64 + n * 16 + r16;
#pragma unroll
            for (int j = 0; j < 4; j++) {
                int p = pr + j;
                if (p < M) {
                    if constexpr (EPI == 1) {
                        float v = acc[m][n][j] + be[f];
                        float ex = __expf(v * (1.5957691216f + 0.0713548162f * v * v));
                        v = v - v / (ex + 1.0f);
                        h_out[(size_t)(hb + p) * DFF + f] = f2bf(v);
                    } else if constexpr (EPI == 2) {
                        out[(size_t)(hb + p) * DM + f] = acc[m][n][j];
                    } else {
                        atomicAdd(out + (size_t)le[p] * DM + f,
                                  we[p] * (acc[m][n][j] + be[f]));
                    }
                }
            }
        }
    }
}

// ---------------- combine: out[t] = w1*(pair[s1]+b2[e1]) + w2*(pair[s2]+b2[e2]) ----
__global__ __launch_bounds__(256) void combine_kernel(const float* __restrict__ pairOut,
                                                      const float* __restrict__ b2,
                                                      const int4* __restrict__ tokIE,
                                                      const float2* __restrict__ tokW,
                                                      const int* __restrict__ baseArr,
                                                      float* __restrict__ out) {
    int t = blockIdx.x;
    int c = threadIdx.x * 4;
    int4 ie = tokIE[t];
    float2 w = tokW[t];
    int s1 = baseArr[ie.x] + ie.y, s2 = baseArr[ie.z] + ie.w;
    f32x4 v1 = *(const f32x4*)(pairOut + (size_t)s1 * DM + c);
    f32x4 v2 = *(const f32x4*)(pairOut + (size_t)s2 * DM + c);
    f32x4 g1 = *(const f32x4*)(b2 + (size_t)ie.x * DM + c);
    f32x4 g2 = *(const f32x4*)(b2 + (size_t)ie.z * DM + c);
    f32x4 res = w.x * (v1 + g1) + w.y * (v2 + g2);
    *(f32x4*)(out + (size_t)t * DM + c) = res;
}

extern "C" void kernel_launch(void* const* d_in, const int* in_sizes, int n_in,
                              void* d_out, int out_size, void* d_ws, size_t ws_size,
                              hipStream_t stream) {
    const float* x  = (const float*)d_in[0];
    const float* gw = (const float*)d_in[1];
    const float* W1 = (const float*)d_in[2];
    const float* b1 = (const float*)d_in[3];
    const float* W2 = (const float*)d_in[4];
    const float* b2 = (const float*)d_in[5];
    float* out = (float*)d_out;

    char* ws = (char*)d_ws;
    size_t o_xb   = 0;
    size_t o_w1t  = (size_t)16 << 20;
    size_t o_w2t  = o_w1t + ((size_t)64 << 20);
    size_t o_h    = o_w2t + ((size_t)64 << 20);           // 144 MiB
    size_t o_pair = o_h + ((size_t)128 << 20);            // 272 MiB
    size_t ctrl_sz = (size_t)1 << 20;
    bool pair_path = ws_size >= o_pair + ((size_t)64 << 20) + ctrl_sz;
    size_t o_ctrl = pair_path ? (o_pair + ((size_t)64 << 20)) : o_pair;

    u16* xb   = (u16*)(ws + o_xb);
    u16* w1t  = (u16*)(ws + o_w1t);
    u16* w2t  = (u16*)(ws + o_w2t);
    u16* h    = (u16*)(ws + o_h);
    float* pairOut = (float*)(ws + o_pair);
    char* ctrl = ws + o_ctrl;
    int*    cnt     = (int*)ctrl;                 // 32B
    float*  psum    = (float*)(ctrl + 32);        // 32B
    float*  indsum  = (float*)(ctrl + 64);        // 32B
    int*    baseArr = (int*)(ctrl + 96);          // 32B
    int*    list    = (int*)(ctrl + 192);         // 256 KiB
    float*  wgt     = (float*)(ctrl + 192 + 262144);   // 256 KiB
    int4*   tokIE   = (int4*)(ctrl + 192 + 524288);    // 128 KiB
    float2* tokW    = (float2*)(ctrl + 192 + 655360);  // 64 KiB
    int*    tileE   = (int*)(ctrl + 192 + 720896);     // 1 KiB
    int*    tileM0  = (int*)(ctrl + 192 + 724992);     // 1 KiB
    int*    nTiles  = (int*)(ctrl + 192 + 729088);     // 4 B

    (void)hipMemsetAsync(ctrl, 0, 192, stream);
    if (!pair_path)
        (void)hipMemsetAsync(d_out, 0, (size_t)out_size * sizeof(float), stream);

    transpose_cvt_kernel<<<dim3(DFF / 32, DM / 64, NE), 256, 0, stream>>>(W1, w1t, DM, DFF);
    transpose_cvt_kernel<<<dim3(DM / 32, DFF / 64, NE), 256, 0, stream>>>(W2, w2t, DFF, DM);
    gate_kernel<<<NTOK / 32, 512, 0, stream>>>(x, gw, xb, cnt, psum, indsum, list, wgt, tokIE, tokW);
    finalize_kernel<<<1, 64, 0, stream>>>(psum, indsum, cnt, baseArr, tileE, tileM0, nTiles,
                                          out + (size_t)NTOK * DM);

    gemm_kernel<DM, 1><<<dim3(NT_MAX * (DFF / 128)), 256, 0, stream>>>(
        xb, w1t, b1, list, wgt, cnt, baseArr, tileE, tileM0, nTiles, h, nullptr);
    if (pair_path) {
        gemm_kernel<DFF, 2><<<dim3(NT_MAX * (DM / 128)), 256, 0, stream>>>(
            h, w2t, b2, list, wgt, cnt, baseArr, tileE, tileM0, nTiles, nullptr, pairOut);
        combine_kernel<<<NTOK, 256, 0, stream>>>(pairOut, b2, tokIE, tokW, baseArr, out);
    } else {
        gemm_kernel<DFF, 3><<<dim3(NT_MAX * (DM / 128)), 256, 0, stream>>>(
            h, w2t, b2, list, wgt, cnt, baseArr, tileE, tileM0, nTiles, nullptr, out);
    }
}

// Round 20
// 526.340 us; speedup vs baseline: 1.0429x; 1.0429x over previous
//
#include <hip/hip_runtime.h>
#include <cstdint>

typedef unsigned short u16;
typedef __attribute__((ext_vector_type(8))) __bf16 bf16x8;
typedef __attribute__((ext_vector_type(4))) float f32x4;

#define NTOK 8192
#define DM   1024
#define DFF  4096
#define NE   8
#define NT_MAX 136

typedef const __attribute__((address_space(1))) unsigned gl_u32;
typedef __attribute__((address_space(3))) unsigned lds_u32;

static __device__ __forceinline__ u16 f2bf(float f) {
    union { float f; unsigned u; } v; v.f = f;
    unsigned r = v.u + 0x7fffu + ((v.u >> 16) & 1u);
    return (u16)(r >> 16);
}

// -------- W [K][F] f32 -> WT [F][K] bf16, per expert in z; 64k x 32f tiles ------
__global__ __launch_bounds__(256) void transpose_cvt_kernel(const float* __restrict__ W,
                                                            u16* __restrict__ WT,
                                                            int K, int F) {
    __shared__ float tile[64][33];
    size_t eo = (size_t)blockIdx.z * K * F;
    const float* src = W + eo;
    u16* dst = WT + eo;
    int k0 = blockIdx.y * 64, f0 = blockIdx.x * 32;
    int tid = threadIdx.x;
    {
        int rk = tid >> 2, cf = (tid & 3) * 8;
        const float* s = src + (size_t)(k0 + rk) * F + f0 + cf;
        f32x4 v0 = *(const f32x4*)(s);
        f32x4 v1 = *(const f32x4*)(s + 4);
#pragma unroll
        for (int i = 0; i < 4; i++) { tile[rk][cf + i] = v0[i]; tile[rk][cf + 4 + i] = v1[i]; }
    }
    __syncthreads();
    {
        int f = tid >> 3, kq = (tid & 7) * 8;
        union { ushort4 h[2]; uint4 q; } o;
#pragma unroll
        for (int i = 0; i < 8; i++) {
            u16 b = f2bf(tile[kq + i][f]);
            ((u16*)&o)[i] = b;
        }
        *(uint4*)(dst + (size_t)(f0 + f) * K + k0 + kq) = o.q;
    }
}

// ------- gate: 512 thr / 8 waves x 4 tokens; block-aggregated routing ------------
__global__ __launch_bounds__(512) void gate_kernel(const float* __restrict__ x,
                                                   const float* __restrict__ gw,
                                                   u16* __restrict__ xb,
                                                   int* __restrict__ cnt,
                                                   float* __restrict__ psum,
                                                   float* __restrict__ indsum,
                                                   int* __restrict__ list,
                                                   float* __restrict__ wgt,
                                                   int4* __restrict__ tokIE,
                                                   float2* __restrict__ tokW) {
    __shared__ float s_psum[NE], s_ind[NE];
    __shared__ int s_cnt[NE], s_base[NE];
    __shared__ int s_tok[NE][32];
    __shared__ float s_wgt[NE][32];
    __shared__ int s_e1[32], s_p1[32], s_e2[32], s_p2[32];
    __shared__ float s_w1[32], s_w2[32];
    int tid = threadIdx.x, lane = tid & 63, wid = tid >> 6;
    if (tid < NE) { s_psum[tid] = 0.f; s_ind[tid] = 0.f; s_cnt[tid] = 0; }
    __syncthreads();
#pragma unroll 1
    for (int it = 0; it < 4; it++) {
        int sl = wid * 4 + it;
        int t = blockIdx.x * 32 + sl;
        const float* xr = x + (size_t)t * DM;
        float xv[16];
#pragma unroll
        for (int i = 0; i < 4; i++) {
            f32x4 v = *(const f32x4*)(xr + i * 256 + lane * 4);
            xv[4 * i + 0] = v[0]; xv[4 * i + 1] = v[1];
            xv[4 * i + 2] = v[2]; xv[4 * i + 3] = v[3];
            ushort4 o;
            o.x = f2bf(v[0]); o.y = f2bf(v[1]); o.z = f2bf(v[2]); o.w = f2bf(v[3]);
            *(ushort4*)(xb + (size_t)t * DM + i * 256 + lane * 4) = o;
        }
        float p[NE];
#pragma unroll
        for (int e = 0; e < NE; e++) {
            const float* gr = gw + (size_t)e * DM;
            float d = 0.f;
#pragma unroll
            for (int i = 0; i < 4; i++) {
                f32x4 g = *(const f32x4*)(gr + i * 256 + lane * 4);
                d += xv[4 * i] * g[0] + xv[4 * i + 1] * g[1]
                   + xv[4 * i + 2] * g[2] + xv[4 * i + 3] * g[3];
            }
#pragma unroll
            for (int off = 32; off; off >>= 1) d += __shfl_xor(d, off);
            p[e] = d;   // GATE_TEMP == 1
        }
        float m = p[0];
#pragma unroll
        for (int e = 1; e < NE; e++) m = fmaxf(m, p[e]);
        float s = 0.f;
#pragma unroll
        for (int e = 0; e < NE; e++) { p[e] = expf(p[e] - m); s += p[e]; }
        float inv = 1.f / s;
#pragma unroll
        for (int e = 0; e < NE; e++) p[e] *= inv;
        int i1 = 0; float p1 = p[0];
#pragma unroll
        for (int e = 1; e < NE; e++) if (p[e] > p1) { p1 = p[e]; i1 = e; }
        int i2 = (i1 == 0) ? 1 : 0; float p2 = p[i2];
#pragma unroll
        for (int e = 0; e < NE; e++) if (e != i1 && p[e] > p2) { p2 = p[e]; i2 = e; }
        float wnorm = 1.f / (p1 + p2);
        if (lane == 0) {
#pragma unroll
            for (int e = 0; e < NE; e++) {
                atomicAdd(&s_psum[e], p[e]);
                atomicAdd(&s_ind[e], (p[e] > 0.f) ? 1.f : 0.f);
            }
            int pos1 = atomicAdd(&s_cnt[i1], 1);
            s_tok[i1][pos1] = t; s_wgt[i1][pos1] = p1 * wnorm;
            int pos2 = atomicAdd(&s_cnt[i2], 1);
            s_tok[i2][pos2] = t; s_wgt[i2][pos2] = p2 * wnorm;
            s_e1[sl] = i1; s_p1[sl] = pos1; s_w1[sl] = p1 * wnorm;
            s_e2[sl] = i2; s_p2[sl] = pos2; s_w2[sl] = p2 * wnorm;
        }
    }
    __syncthreads();
    if (tid < NE) {
        s_base[tid] = atomicAdd(&cnt[tid], s_cnt[tid]);
        atomicAdd(&psum[tid], s_psum[tid]);
        atomicAdd(&indsum[tid], s_ind[tid]);
    }
    __syncthreads();
    for (int idx = tid; idx < NE * 32; idx += 512) {
        int e = idx >> 5, j = idx & 31;
        if (j < s_cnt[e]) {
            list[e * NTOK + s_base[e] + j] = s_tok[e][j];
            wgt[e * NTOK + s_base[e] + j] = s_wgt[e][j];
        }
    }
    if (tid < 32) {
        int t = blockIdx.x * 32 + tid;
        int e1 = s_e1[tid], e2 = s_e2[tid];
        tokIE[t] = make_int4(e1, s_base[e1] + s_p1[tid], e2, s_base[e2] + s_p2[tid]);
        tokW[t] = make_float2(s_w1[tid], s_w2[tid]);
    }
}

// ---------------- finalize: aux loss + expert bases + flat tile worklist ----------
__global__ void finalize_kernel(const float* __restrict__ psum,
                                const float* __restrict__ indsum,
                                const int* __restrict__ cnt,
                                int* __restrict__ baseArr,
                                int* __restrict__ tileE,
                                int* __restrict__ tileM0,
                                int* __restrict__ nTiles,
                                float* __restrict__ out_aux) {
    if (threadIdx.x == 0) {
        float a = 0.f; int b = 0, nt = 0;
        for (int e = 0; e < NE; e++) {
            a += (psum[e] * (1.f / NTOK)) * (indsum[e] * (1.f / NTOK));
            baseArr[e] = b; b += cnt[e];
            int mt = (cnt[e] + 127) >> 7;
            for (int i = 0; i < mt; i++) { tileE[nt] = e; tileM0[nt] = i; nt++; }
        }
        nTiles[0] = nt;
        out_aux[0] = a * (float)NE * 0.01f;
    }
}

// ---------------- m97-style single-buffer bf16 MFMA GEMM: 128x128, BK=64 ---------
// R13/R17 champion, byte-identical: launch_bounds(256,4) pins 64 VGPR (R19
// showed dropping the floor lets VGPR grow to 84 and occupancy FALL to 29%).
// 32 KiB LDS -> ~4 blocks/CU; cross-block overlap covers staging drain (m114).
// T2 both-sides swizzle; T5 setprio; band worklist + bijective XCD chunking.
// EPI==1: A = xb gathered via list; epilogue fast-gelu -> h[hb+p]
// EPI==2: A = h[hb+p]; epilogue pairOut[hb+p] = acc
// EPI==3: A = h[hb+p]; epilogue atomicAdd(out[tok], wgt*(acc+bias))  (fallback)
template <int KDIM, int EPI>
__global__ __launch_bounds__(256, 4) void gemm_kernel(const u16* __restrict__ A,
                                                      const u16* __restrict__ BT,
                                                      const float* __restrict__ bias,
                                                      const int* __restrict__ list,
                                                      const float* __restrict__ wgt,
                                                      const int* __restrict__ cnt,
                                                      const int* __restrict__ base,
                                                      const int* __restrict__ tileE,
                                                      const int* __restrict__ tileM0,
                                                      const int* __restrict__ nTiles,
                                                      u16* __restrict__ h_out,
                                                      float* __restrict__ out) {
    constexpr int NCOL = (EPI == 1) ? DFF : DM;
    constexpr int NY = NCOL / 128;
    constexpr int NT = KDIM / 64;
    constexpr int BAND = 4 * NY;
    int nwg = gridDim.x;
    int q = nwg >> 3, r = nwg & 7;
    int xcd = blockIdx.x & 7, idx0 = blockIdx.x >> 3;
    int wg = (xcd < r ? xcd * (q + 1) : r * (q + 1) + (xcd - r) * q) + idx0;
    int band = wg / BAND, ib = wg - band * BAND;
    int ny = ib >> 2;
    int t = band * 4 + (ib & 3);
    if (t >= nTiles[0]) return;
    int e = tileE[t];
    int m0 = tileM0[t] << 7;
    int M = cnt[e];
    int hb = base[e];
    int n0 = ny * 128;
    const int* le = list + e * NTOK;
    const float* we = wgt + e * NTOK;
    const u16* Bte = BT + (size_t)e * NCOL * KDIM;
    const float* be = bias + (size_t)e * NCOL;

    // single-buffered: 16 KiB A + 16 KiB B = 32 KiB
    __shared__ __attribute__((aligned(16))) u16 lA[128 * 64];
    __shared__ __attribute__((aligned(16))) u16 lB[128 * 64];

    int tid = threadIdx.x;
    int lane = tid & 63, wid = tid >> 6;
    int wr = wid >> 1, wc = wid & 1;
    int r16 = lane & 15, hi = lane >> 4;
    int r8 = r16 & 7;

    const u16* aG[4]; const u16* bG[4]; int lofs[4];
#pragma unroll
    for (int qq = 0; qq < 4; qq++) {
        int lin = qq * 256 + tid;
        int row = lin >> 3, j = lin & 7;
        int js = j ^ (row & 7);                     // source-side swizzle
        lofs[qq] = lin * 8;
        int pos = m0 + row; if (pos > M - 1) pos = M - 1;
        size_t arow = (EPI == 1) ? (size_t)le[pos] : (size_t)(hb + pos);
        aG[qq] = A + arow * KDIM + js * 8;
        bG[qq] = Bte + (size_t)(n0 + row) * KDIM + js * 8;
    }

#define STAGE(k0)                                                                   \
    do {                                                                            \
        _Pragma("unroll")                                                           \
        for (int qq = 0; qq < 4; qq++) {                                            \
            __builtin_amdgcn_global_load_lds((gl_u32*)(aG[qq] + (k0)),              \
                (lds_u32*)(lA + lofs[qq]), 16, 0, 0);                               \
            __builtin_amdgcn_global_load_lds((gl_u32*)(bG[qq] + (k0)),              \
                (lds_u32*)(lB + lofs[qq]), 16, 0, 0);                               \
        }                                                                           \
    } while (0)

    f32x4 acc[4][4];
#pragma unroll
    for (int m = 0; m < 4; m++)
#pragma unroll
        for (int n = 0; n < 4; n++) acc[m][n] = (f32x4){0.f, 0.f, 0.f, 0.f};

    STAGE(0);

#pragma unroll 1
    for (int tI = 0; tI < NT; ++tI) {
        // tile tI staged by every wave -> visible after barrier
        asm volatile("s_waitcnt vmcnt(0)" ::: "memory");
        __builtin_amdgcn_s_barrier();
#pragma unroll
        for (int kk = 0; kk < 2; kk++) {
            bf16x8 aF[4], bF[4];
            int ch = ((kk << 2) | hi) ^ r8;         // read-side swizzle
#pragma unroll
            for (int m = 0; m < 4; m++)
                aF[m] = *(const bf16x8*)(lA + ((wr * 64 + m * 16 + r16) << 6) + (ch << 3));
#pragma unroll
            for (int n = 0; n < 4; n++)
                bF[n] = *(const bf16x8*)(lB + ((wc * 64 + n * 16 + r16) << 6) + (ch << 3));
            __builtin_amdgcn_s_setprio(1);
#pragma unroll
            for (int m = 0; m < 4; m++)
#pragma unroll
                for (int n = 0; n < 4; n++)
                    acc[m][n] = __builtin_amdgcn_mfma_f32_16x16x32_bf16(aF[m], bF[n], acc[m][n], 0, 0, 0);
            __builtin_amdgcn_s_setprio(0);
        }
        // all reads done -> safe to overwrite buffer with next tile
        asm volatile("s_waitcnt lgkmcnt(0)" ::: "memory");
        __builtin_amdgcn_s_barrier();
        if (tI + 1 < NT) STAGE((tI + 1) * 64);
    }
#undef STAGE

#pragma unroll
    for (int m = 0; m < 4; m++) {
        int pr = m0 + wr * 64 + m * 16 + hi * 4;
#pragma unroll
        for (int n = 0; n < 4; n++) {
            int f = n0 + wc * 64 + n * 16 + r16;
#pragma unroll
            for (int j = 0; j < 4; j++) {
                int p = pr + j;
                if (p < M) {
                    if constexpr (EPI == 1) {
                        float v = acc[m][n][j] + be[f];
                        float ex = __expf(v * (1.5957691216f + 0.0713548162f * v * v));
                        v = v - v / (ex + 1.0f);
                        h_out[(size_t)(hb + p) * DFF + f] = f2bf(v);
                    } else if constexpr (EPI == 2) {
                        out[(size_t)(hb + p) * DM + f] = acc[m][n][j];
                    } else {
                        atomicAdd(out + (size_t)le[p] * DM + f,
                                  we[p] * (acc[m][n][j] + be[f]));
                    }
                }
            }
        }
    }
}

// ---------------- combine: out[t] = w1*(pair[s1]+b2[e1]) + w2*(pair[s2]+b2[e2]) ----
__global__ __launch_bounds__(256) void combine_kernel(const float* __restrict__ pairOut,
                                                      const float* __restrict__ b2,
                                                      const int4* __restrict__ tokIE,
                                                      const float2* __restrict__ tokW,
                                                      const int* __restrict__ baseArr,
                                                      float* __restrict__ out) {
    int t = blockIdx.x;
    int c = threadIdx.x * 4;
    int4 ie = tokIE[t];
    float2 w = tokW[t];
    int s1 = baseArr[ie.x] + ie.y, s2 = baseArr[ie.z] + ie.w;
    f32x4 v1 = *(const f32x4*)(pairOut + (size_t)s1 * DM + c);
    f32x4 v2 = *(const f32x4*)(pairOut + (size_t)s2 * DM + c);
    f32x4 g1 = *(const f32x4*)(b2 + (size_t)ie.x * DM + c);
    f32x4 g2 = *(const f32x4*)(b2 + (size_t)ie.z * DM + c);
    f32x4 res = w.x * (v1 + g1) + w.y * (v2 + g2);
    *(f32x4*)(out + (size_t)t * DM + c) = res;
}

extern "C" void kernel_launch(void* const* d_in, const int* in_sizes, int n_in,
                              void* d_out, int out_size, void* d_ws, size_t ws_size,
                              hipStream_t stream) {
    const float* x  = (const float*)d_in[0];
    const float* gw = (const float*)d_in[1];
    const float* W1 = (const float*)d_in[2];
    const float* b1 = (const float*)d_in[3];
    const float* W2 = (const float*)d_in[4];
    const float* b2 = (const float*)d_in[5];
    float* out = (float*)d_out;

    char* ws = (char*)d_ws;
    size_t o_xb   = 0;
    size_t o_w1t  = (size_t)16 << 20;
    size_t o_w2t  = o_w1t + ((size_t)64 << 20);
    size_t o_h    = o_w2t + ((size_t)64 << 20);           // 144 MiB
    size_t o_pair = o_h + ((size_t)128 << 20);            // 272 MiB
    size_t ctrl_sz = (size_t)1 << 20;
    bool pair_path = ws_size >= o_pair + ((size_t)64 << 20) + ctrl_sz;
    size_t o_ctrl = pair_path ? (o_pair + ((size_t)64 << 20)) : o_pair;

    u16* xb   = (u16*)(ws + o_xb);
    u16* w1t  = (u16*)(ws + o_w1t);
    u16* w2t  = (u16*)(ws + o_w2t);
    u16* h    = (u16*)(ws + o_h);
    float* pairOut = (float*)(ws + o_pair);
    char* ctrl = ws + o_ctrl;
    int*    cnt     = (int*)ctrl;                 // 32B
    float*  psum    = (float*)(ctrl + 32);        // 32B
    float*  indsum  = (float*)(ctrl + 64);        // 32B
    int*    baseArr = (int*)(ctrl + 96);          // 32B
    int*    list    = (int*)(ctrl + 192);         // 256 KiB
    float*  wgt     = (float*)(ctrl + 192 + 262144);   // 256 KiB
    int4*   tokIE   = (int4*)(ctrl + 192 + 524288);    // 128 KiB
    float2* tokW    = (float2*)(ctrl + 192 + 655360);  // 64 KiB
    int*    tileE   = (int*)(ctrl + 192 + 720896);     // 1 KiB
    int*    tileM0  = (int*)(ctrl + 192 + 724992);     // 1 KiB
    int*    nTiles  = (int*)(ctrl + 192 + 729088);     // 4 B

    (void)hipMemsetAsync(ctrl, 0, 192, stream);
    if (!pair_path)
        (void)hipMemsetAsync(d_out, 0, (size_t)out_size * sizeof(float), stream);

    transpose_cvt_kernel<<<dim3(DFF / 32, DM / 64, NE), 256, 0, stream>>>(W1, w1t, DM, DFF);
    transpose_cvt_kernel<<<dim3(DM / 32, DFF / 64, NE), 256, 0, stream>>>(W2, w2t, DFF, DM);
    gate_kernel<<<NTOK / 32, 512, 0, stream>>>(x, gw, xb, cnt, psum, indsum, list, wgt, tokIE, tokW);
    finalize_kernel<<<1, 64, 0, stream>>>(psum, indsum, cnt, baseArr, tileE, tileM0, nTiles,
                                          out + (size_t)NTOK * DM);

    gemm_kernel<DM, 1><<<dim3(NT_MAX * (DFF / 128)), 256, 0, stream>>>(
        xb, w1t, b1, list, wgt, cnt, baseArr, tileE, tileM0, nTiles, h, nullptr);
    if (pair_path) {
        gemm_kernel<DFF, 2><<<dim3(NT_MAX * (DM / 128)), 256, 0, stream>>>(
            h, w2t, b2, list, wgt, cnt, baseArr, tileE, tileM0, nTiles, nullptr, pairOut);
        combine_kernel<<<NTOK, 256, 0, stream>>>(pairOut, b2, tokIE, tokW, baseArr, out);
    } else {
        gemm_kernel<DFF, 3><<<dim3(NT_MAX * (DM / 128)), 256, 0, stream>>>(
            h, w2t, b2, list, wgt, cnt, baseArr, tileE, tileM0, nTiles, nullptr, out);
    }
}